// Round 7
// baseline (1085.457 us; speedup 1.0000x reference)
//
#include <hip/hip_runtime.h>
#include <math.h>

#define B 8
#define N 4096
#define S 1024
#define K 32
#define CIN 64
#define DIM 128
#define NH 4
#define HD 32
#define PTROW 68   // xyz(3) + points(64) + pad(1)
#define NT_BLOCKS 240

typedef __attribute__((ext_vector_type(8))) short bfrag;
typedef __attribute__((ext_vector_type(4))) float f32x4;

#define MFMA(a, b, c) __builtin_amdgcn_mfma_f32_16x16x32_bf16((a), (b), (c), 0, 0, 0)

__device__ __forceinline__ unsigned short f2bf(float f) {
    union { float f; unsigned u; } v; v.f = f;
    unsigned r = v.u + 0x7FFFu + ((v.u >> 16) & 1u);
    return (unsigned short)(r >> 16);
}

// float max DPP step; invalid lanes keep old -> fmax(v,v)=v safe
#define DPPMAXF(var, CTRL) {                                                              \
    int _o = __builtin_amdgcn_update_dpp(__float_as_int(var), __float_as_int(var),        \
                                         CTRL, 0xf, 0xf, false);                          \
    var = fmaxf(var, __int_as_float(_o));                                                 \
}
#define DPPMINU(var, CTRL) {                                                              \
    unsigned _o = (unsigned)__builtin_amdgcn_update_dpp((int)(var), (int)(var),           \
                                                        CTRL, 0xf, 0xf, false);          \
    var = (_o < (var)) ? _o : (var);                                                      \
}

// ---------------- mega kernel: FPS (blk<8) | transpose | weight-swizzle | bias ----------------
__global__ __launch_bounds__(256) void k_mega(
    const float* __restrict__ xyz, const float* __restrict__ points,
    const float* __restrict__ Wc, const float* __restrict__ bc,
    const float* __restrict__ gamma, const float* __restrict__ beta,
    const float* __restrict__ mean, const float* __restrict__ var,
    const float* __restrict__ Wp, const float* __restrict__ bp,
    const float* __restrict__ Wq, const float* __restrict__ Wk,
    const float* __restrict__ Wv, const float* __restrict__ Wo,
    float* __restrict__ ptsT, float* __restrict__ nxyz, float* __restrict__ out_xyz,
    unsigned short* __restrict__ WF, float* __restrict__ biasv) {
    __shared__ __align__(16) float pxyz4[N * 4];  // 64 KB: [n] = {x,y,z,pad}
    __shared__ float cent[S * 3];                 // 12 KB
    __shared__ __align__(16) unsigned long long wbuf[2][4];
    const int tid = threadIdx.x;
    int blk = blockIdx.x;

    if (blk < 8) {
        // ================= FPS =================
        const int b = blk;
        const float* X = xyz + (size_t)b * 3 * N;
        float pd[16];
#pragma unroll
        for (int i = 0; i < 16; i++) {
            int n = tid + i * 256;
            pxyz4[n * 4 + 0] = X[n];
            pxyz4[n * 4 + 1] = X[N + n];
            pxyz4[n * 4 + 2] = X[2 * N + n];
            pd[i] = 1e10f;
        }
        __syncthreads();
        float cx = pxyz4[0], cy = pxyz4[1], cz = pxyz4[2];

        for (int t = 0; t < S; t++) {
            if (tid == 0) { cent[t * 3] = cx; cent[t * 3 + 1] = cy; cent[t * 3 + 2] = cz; }
            if (t == S - 1) break;

            float bv = -1.0f; int slot = 0;
#pragma unroll
            for (int i = 0; i < 16; i++) {
                const float4 p = *(const float4*)&pxyz4[(tid + i * 256) * 4];
                float dx = p.x - cx, dy = p.y - cy, dz = p.z - cz;
                // match XLA/np: (dx*dx + dy*dy) + dz*dz, no FMA contraction
                float d = __fadd_rn(__fadd_rn(__fmul_rn(dx, dx), __fmul_rn(dy, dy)), __fmul_rn(dz, dz));
                float pn = fminf(pd[i], d);
                pd[i] = pn;
                bool gt = pn > bv;          // strict >: first slot wins within thread
                bv = gt ? pn : bv;
                slot = gt ? i : slot;
            }
            // wave float-max (lane63 gets wave max)
            float m = bv;
            DPPMAXF(m, 0x111)  // row_shr:1
            DPPMAXF(m, 0x112)  // row_shr:2
            DPPMAXF(m, 0x114)  // row_shr:4
            DPPMAXF(m, 0x118)  // row_shr:8
            DPPMAXF(m, 0x142)  // row_bcast:15
            DPPMAXF(m, 0x143)  // row_bcast:31
            float wmax = __int_as_float(__builtin_amdgcn_readlane(__float_as_int(m), 63));
            // min index among tied lanes
            unsigned bi = (unsigned)(tid + (slot << 8));
            unsigned bic = (bv == wmax) ? bi : 0xFFFFFFFFu;
            DPPMINU(bic, 0x111)
            DPPMINU(bic, 0x112)
            DPPMINU(bic, 0x114)
            DPPMINU(bic, 0x118)
            DPPMINU(bic, 0x142)
            DPPMINU(bic, 0x143)
            if ((tid & 63) == 63) {
                unsigned long long key =
                    ((unsigned long long)__float_as_uint(wmax) << 32) | (0xFFFFFFFFu - bic);
                wbuf[t & 1][tid >> 6] = key;
            }
            __syncthreads();
            ulonglong2 ab = *(const ulonglong2*)&wbuf[t & 1][0];
            ulonglong2 cd = *(const ulonglong2*)&wbuf[t & 1][2];
            unsigned long long kA = ab.x > ab.y ? ab.x : ab.y;
            unsigned long long kB = cd.x > cd.y ? cd.x : cd.y;
            unsigned long long km = kA > kB ? kA : kB;
            int best = (int)(0xFFFFFFFFu - (unsigned)km);
            const float4 pc = *(const float4*)&pxyz4[best * 4];
            cx = pc.x; cy = pc.y; cz = pc.z;
        }
        __syncthreads();
        for (int i = tid; i < S; i += 256) {
            float a = cent[i * 3], c1 = cent[i * 3 + 1], c2 = cent[i * 3 + 2];
            nxyz[(b * S + i) * 3 + 0] = a;
            nxyz[(b * S + i) * 3 + 1] = c1;
            nxyz[(b * S + i) * 3 + 2] = c2;
            out_xyz[b * 3 * S + i] = a;
            out_xyz[b * 3 * S + S + i] = c1;
            out_xyz[b * 3 * S + 2 * S + i] = c2;
        }
        return;
    }
    blk -= 8;
    if (blk < NT_BLOCKS) {
        // ================= transpose (coalesced reads, L2-absorbed scattered writes) =================
        for (int task = blk; task < B * 67; task += NT_BLOCKS) {
            int b = task / 67, c = task % 67;
            const float* src = (c < 3) ? &xyz[(b * 3 + c) * N] : &points[(b * CIN + (c - 3)) * N];
            float* dst = ptsT + (size_t)b * N * PTROW + c;
            for (int n = tid; n < N; n += 256)
                dst[(size_t)n * PTROW] = src[n];
        }
        return;
    }
    blk -= NT_BLOCKS;
    if (blk < 19) {
        // ================= weight swizzle into MFMA B-fragment order =================
        int mat, kt, base;
        if (blk < 3) { mat = 0; kt = blk; base = 0; }
        else { mat = 1 + (blk - 3) / 4; kt = (blk - 3) % 4; base = 12288 + (mat - 1) * 16384; }
        const float* W = (mat == 1) ? Wq : (mat == 2) ? Wk : (mat == 3) ? Wv : Wo;
        const int lane = tid & 63;
#pragma unroll
        for (int g2 = 0; g2 < 2; g2++) {
            int gnt = (tid >> 6) * 2 + g2;
            int n = gnt * 16 + (lane & 15);
            int k0 = kt * 32 + (lane >> 4) * 8;
            unsigned short* dst = WF + base + (size_t)((kt * 8 + gnt) * 64 + lane) * 8;
            float a = (mat == 0) ? (gamma[n] / sqrtf(var[n] + 1e-5f)) : 0.0f;
#pragma unroll
            for (int i = 0; i < 8; i++) {
                int k = k0 + i;
                float v;
                if (mat == 0) v = (k < 67) ? Wc[n * 67 + k] * a : (k < 70) ? Wp[(k - 67) * 128 + n] : 0.0f;
                else v = W[k * 128 + n];
                dst[i] = f2bf(v);
            }
        }
        return;
    }
    // ================= bias =================
    if (tid < DIM) {
        float a = gamma[tid] / sqrtf(var[tid] + 1e-5f);
        biasv[tid] = bc[tid] * a + beta[tid] - mean[tid] * a + bp[tid];
    }
}

// ---------------- ball query ----------------
__global__ void k_ball(const float* __restrict__ xyz, const float* __restrict__ nxyz,
                       int* __restrict__ gidx) {
    const int g = blockIdx.x * 4 + (threadIdx.x >> 6);
    const int lane = threadIdx.x & 63;
    const int b = g >> 10;
    const float* X = xyz + (size_t)b * 3 * N;
    float cx = nxyz[g * 3 + 0], cy = nxyz[g * 3 + 1], cz = nxyz[g * 3 + 2];
    int cnt = 0;
    int first = -1;
    for (int base = 0; base < N && cnt < K; base += 64) {
        int n = base + lane;
        float dx = cx - X[n], dy = cy - X[N + n], dz = cz - X[2 * N + n];
        float d = __fadd_rn(__fadd_rn(__fmul_rn(dx, dx), __fmul_rn(dy, dy)), __fmul_rn(dz, dz));
        bool in = (d <= 0.04f);
        unsigned long long m = __ballot(in);
        int pre = __popcll(m & ((1ull << lane) - 1ull));
        if (in && cnt + pre < K) gidx[g * K + cnt + pre] = n;
        if (first < 0 && m) first = base + (int)__ffsll((unsigned long long)m) - 1;
        cnt += __popcll(m);
    }
    if (cnt < K) {
        for (int i = cnt + lane; i < K; i += 64) gidx[g * K + i] = first;
    }
}

// ---------------- fused group kernel, MFMA version ----------------
#define LDS_X   0        // [32][128] bf16 swizzled: x -> P
#define LDS_A   8192     // [32][128] bf16 swizzled: feat -> q -> o
#define LDS_K   16384    // [32][128] bf16 swizzled: k
#define LDS_VT  24576    // v_t [128][56] bf16 (112B rows): v transposed
#define LDS_MISC 38912   // nidx[32] int, ctr[3] float
#define LDS_TOTAL 39056

#define LDSA_READ(off, row, colb) \
    (*(const bfrag*)(smem + (off) + ((row) << 8) + ((colb) ^ (((row) & 7) << 4))))
#define LDS_ST16(off, row, colb, val) \
    (*(unsigned short*)(smem + (off) + ((row) << 8) + ((colb) ^ (((row) & 7) << 4))) = (val))

__global__ __launch_bounds__(256, 4) void k_group(
    const float* __restrict__ ptsT, const float* __restrict__ nxyz,
    const int* __restrict__ gidx, const unsigned short* __restrict__ WF,
    const float* __restrict__ bias, float* __restrict__ outp) {
    __shared__ __align__(16) char smem[LDS_TOTAL];
    const int g = blockIdx.x, b = g >> 10, s = g & 1023;
    const int tid = threadIdx.x;
    const int w = tid >> 6, l = tid & 63;
    const int lane16 = l & 15, lquad = l >> 4;
    const int ncol = w * 32;

    int* nidx = (int*)(smem + LDS_MISC);
    float* ctr = (float*)(smem + LDS_MISC + 128);

    if (tid < K) nidx[tid] = gidx[g * K + tid];
    if (tid >= 64 && tid < 67) ctr[tid - 64] = nxyz[g * 3 + (tid - 64)];
    for (int i = tid; i < 32 * 32; i += 256) {
        int p = i >> 5, c = 64 + (i & 31);
        LDS_ST16(LDS_A, p, c * 2, (unsigned short)0);
    }
    __syncthreads();

    {
        const int p = tid >> 3, j = tid & 7;
        const float* src = ptsT + (size_t)(b * N + nidx[p]) * PTROW;
        float c0 = ctr[0], c1 = ctr[1], c2 = ctr[2];
        for (int c = j; c < 70; c += 8) {
            float v;
            if (c < 3) v = src[c] - (c == 0 ? c0 : c == 1 ? c1 : c2);
            else if (c < 67) v = src[c];
            else v = src[c - 67];
            LDS_ST16(LDS_A, p, c * 2, f2bf(v));
        }
    }
    __syncthreads();

    // ---- GEMM1: x = feat @ Wall + bias ----
    f32x4 accx[2][2];
    {
        float bv0 = bias[ncol + lane16], bv1 = bias[ncol + 16 + lane16];
        accx[0][0] = f32x4{bv0, bv0, bv0, bv0}; accx[1][0] = accx[0][0];
        accx[0][1] = f32x4{bv1, bv1, bv1, bv1}; accx[1][1] = accx[0][1];
        const bfrag* WallF = (const bfrag*)WF;
#pragma unroll
        for (int kt = 0; kt < 3; kt++) {
            bfrag a0 = LDSA_READ(LDS_A, lane16, kt * 64 + lquad * 16);
            bfrag a1 = LDSA_READ(LDS_A, 16 + lane16, kt * 64 + lquad * 16);
            bfrag b0 = WallF[(kt * 8 + w * 2 + 0) * 64 + l];
            bfrag b1 = WallF[(kt * 8 + w * 2 + 1) * 64 + l];
            accx[0][0] = MFMA(a0, b0, accx[0][0]);
            accx[0][1] = MFMA(a0, b1, accx[0][1]);
            accx[1][0] = MFMA(a1, b0, accx[1][0]);
            accx[1][1] = MFMA(a1, b1, accx[1][1]);
        }
#pragma unroll
        for (int mt = 0; mt < 2; mt++)
#pragma unroll
            for (int nt = 0; nt < 2; nt++)
#pragma unroll
                for (int r = 0; r < 4; r++)
                    LDS_ST16(LDS_X, mt * 16 + lquad * 4 + r, (ncol + nt * 16 + lane16) * 2,
                             f2bf(accx[mt][nt][r]));
    }
    __syncthreads();

    // ---- GEMM2-4: q,k,v = x @ {Wq,Wk,Wv} ----
    {
        const bfrag* WQF = (const bfrag*)(WF + 12288);
        const bfrag* WKF = (const bfrag*)(WF + 28672);
        const bfrag* WVF = (const bfrag*)(WF + 45056);
#pragma unroll
        for (int m = 0; m < 3; m++) {
            const bfrag* BW = (m == 0) ? WQF : (m == 1) ? WKF : WVF;
            f32x4 acc[2][2] = {};
#pragma unroll
            for (int kt = 0; kt < 4; kt++) {
                bfrag a0 = LDSA_READ(LDS_X, lane16, kt * 64 + lquad * 16);
                bfrag a1 = LDSA_READ(LDS_X, 16 + lane16, kt * 64 + lquad * 16);
                bfrag b0 = BW[(kt * 8 + w * 2 + 0) * 64 + l];
                bfrag b1 = BW[(kt * 8 + w * 2 + 1) * 64 + l];
                acc[0][0] = MFMA(a0, b0, acc[0][0]);
                acc[0][1] = MFMA(a0, b1, acc[0][1]);
                acc[1][0] = MFMA(a1, b0, acc[1][0]);
                acc[1][1] = MFMA(a1, b1, acc[1][1]);
            }
            if (m < 2) {
                int dst = (m == 0) ? LDS_A : LDS_K;
#pragma unroll
                for (int mt = 0; mt < 2; mt++)
#pragma unroll
                    for (int nt = 0; nt < 2; nt++)
#pragma unroll
                        for (int r = 0; r < 4; r++)
                            LDS_ST16(dst, mt * 16 + lquad * 4 + r, (ncol + nt * 16 + lane16) * 2,
                                     f2bf(acc[mt][nt][r]));
            } else {
#pragma unroll
                for (int mt = 0; mt < 2; mt++)
#pragma unroll
                    for (int nt = 0; nt < 2; nt++)
#pragma unroll
                        for (int r = 0; r < 4; r++) {
                            int d = ncol + nt * 16 + lane16;
                            int j = mt * 16 + lquad * 4 + r;
                            *(unsigned short*)(smem + LDS_VT + d * 112 + j * 2) = f2bf(acc[mt][nt][r]);
                        }
            }
        }
    }
    __syncthreads();

    // ---- scores (head h = w), in-register softmax, P -> LDS_X, PV, o -> LDS_A ----
    {
        const int h = w;
        const int hb = h * 64;
        bfrag aq0 = LDSA_READ(LDS_A, lane16, hb + lquad * 16);
        bfrag aq1 = LDSA_READ(LDS_A, 16 + lane16, hb + lquad * 16);
        bfrag bk0 = LDSA_READ(LDS_K, lane16, hb + lquad * 16);
        bfrag bk1 = LDSA_READ(LDS_K, 16 + lane16, hb + lquad * 16);
        f32x4 sc[2][2] = {};
        sc[0][0] = MFMA(aq0, bk0, sc[0][0]);
        sc[0][1] = MFMA(aq0, bk1, sc[0][1]);
        sc[1][0] = MFMA(aq1, bk0, sc[1][0]);
        sc[1][1] = MFMA(aq1, bk1, sc[1][1]);

        const float scale = 0.17677669529663687f;
        float p_[2][2][4];
        float mx[2][4], sm[2][4];
#pragma unroll
        for (int mt = 0; mt < 2; mt++)
#pragma unroll
            for (int r = 0; r < 4; r++) {
                p_[mt][0][r] = sc[mt][0][r] * scale;
                p_[mt][1][r] = sc[mt][1][r] * scale;
                mx[mt][r] = fmaxf(p_[mt][0][r], p_[mt][1][r]);
            }
#pragma unroll
        for (int d = 1; d < 16; d <<= 1)
#pragma unroll
            for (int mt = 0; mt < 2; mt++)
#pragma unroll
                for (int r = 0; r < 4; r++)
                    mx[mt][r] = fmaxf(mx[mt][r], __shfl_xor(mx[mt][r], d));
#pragma unroll
        for (int mt = 0; mt < 2; mt++)
#pragma unroll
            for (int r = 0; r < 4; r++) {
                float e0 = __expf(p_[mt][0][r] - mx[mt][r]);
                float e1 = __expf(p_[mt][1][r] - mx[mt][r]);
                p_[mt][0][r] = e0; p_[mt][1][r] = e1;
                sm[mt][r] = e0 + e1;
            }
#pragma unroll
        for (int d = 1; d < 16; d <<= 1)
#pragma unroll
            for (int mt = 0; mt < 2; mt++)
#pragma unroll
                for (int r = 0; r < 4; r++)
                    sm[mt][r] += __shfl_xor(sm[mt][r], d);
#pragma unroll
        for (int mt = 0; mt < 2; mt++)
#pragma unroll
            for (int r = 0; r < 4; r++) {
                float inv = 1.0f / sm[mt][r];
                int row = mt * 16 + lquad * 4 + r;
                LDS_ST16(LDS_X, row, (h * 32 + lane16) * 2, f2bf(p_[mt][0][r] * inv));
                LDS_ST16(LDS_X, row, (h * 32 + 16 + lane16) * 2, f2bf(p_[mt][1][r] * inv));
            }

        f32x4 oacc[2][2] = {};
        bfrag ap0 = LDSA_READ(LDS_X, lane16, hb + lquad * 16);
        bfrag ap1 = LDSA_READ(LDS_X, 16 + lane16, hb + lquad * 16);
        bfrag bv0 = *(const bfrag*)(smem + LDS_VT + (h * 32 + lane16) * 112 + lquad * 16);
        bfrag bv1 = *(const bfrag*)(smem + LDS_VT + (h * 32 + 16 + lane16) * 112 + lquad * 16);
        oacc[0][0] = MFMA(ap0, bv0, oacc[0][0]);
        oacc[0][1] = MFMA(ap0, bv1, oacc[0][1]);
        oacc[1][0] = MFMA(ap1, bv0, oacc[1][0]);
        oacc[1][1] = MFMA(ap1, bv1, oacc[1][1]);
#pragma unroll
        for (int mt = 0; mt < 2; mt++)
#pragma unroll
            for (int nt = 0; nt < 2; nt++)
#pragma unroll
                for (int r = 0; r < 4; r++)
                    LDS_ST16(LDS_A, mt * 16 + lquad * 4 + r, (h * 32 + nt * 16 + lane16) * 2,
                             f2bf(oacc[mt][nt][r]));
    }
    __syncthreads();

    // ---- GEMM7: out = x + o @ Wo ; maxpool over 32 points ----
    {
        const bfrag* WOF = (const bfrag*)(WF + 61440);
        f32x4 acc[2][2];
#pragma unroll
        for (int mt = 0; mt < 2; mt++)
#pragma unroll
            for (int nt = 0; nt < 2; nt++) acc[mt][nt] = accx[mt][nt];
#pragma unroll
        for (int kt = 0; kt < 4; kt++) {
            bfrag a0 = LDSA_READ(LDS_A, lane16, kt * 64 + lquad * 16);
            bfrag a1 = LDSA_READ(LDS_A, 16 + lane16, kt * 64 + lquad * 16);
            bfrag b0 = WOF[(kt * 8 + w * 2 + 0) * 64 + l];
            bfrag b1 = WOF[(kt * 8 + w * 2 + 1) * 64 + l];
            acc[0][0] = MFMA(a0, b0, acc[0][0]);
            acc[0][1] = MFMA(a0, b1, acc[0][1]);
            acc[1][0] = MFMA(a1, b0, acc[1][0]);
            acc[1][1] = MFMA(a1, b1, acc[1][1]);
        }
        float mnt[2];
#pragma unroll
        for (int nt = 0; nt < 2; nt++) {
            float m = acc[0][nt][0];
#pragma unroll
            for (int r = 1; r < 4; r++) m = fmaxf(m, acc[0][nt][r]);
#pragma unroll
            for (int r = 0; r < 4; r++) m = fmaxf(m, acc[1][nt][r]);
            m = fmaxf(m, __shfl_xor(m, 16));
            m = fmaxf(m, __shfl_xor(m, 32));
            mnt[nt] = m;
        }
        if (lquad == 0) {
#pragma unroll
            for (int nt = 0; nt < 2; nt++) {
                int d = ncol + nt * 16 + lane16;
                outp[((size_t)b * DIM + d) * S + s] = mnt[nt];
            }
        }
    }
}

extern "C" void kernel_launch(void* const* d_in, const int* in_sizes, int n_in,
                              void* d_out, int out_size, void* d_ws, size_t ws_size,
                              hipStream_t stream) {
    const float* xyz = (const float*)d_in[0];
    const float* points = (const float*)d_in[1];
    const float* Wc = (const float*)d_in[2];
    const float* bc = (const float*)d_in[3];
    const float* gamma = (const float*)d_in[4];
    const float* beta = (const float*)d_in[5];
    const float* mean = (const float*)d_in[6];
    const float* var = (const float*)d_in[7];
    const float* Wq = (const float*)d_in[8];
    const float* Wk = (const float*)d_in[9];
    const float* Wv = (const float*)d_in[10];
    const float* Wo = (const float*)d_in[11];
    const float* Wp = (const float*)d_in[12];
    const float* bp = (const float*)d_in[13];

    float* out_xyz = (float*)d_out;
    float* out_pts = out_xyz + B * 3 * S;

    char* ws = (char*)d_ws;
    float* ptsT = (float*)ws;
    size_t off = (size_t)B * N * PTROW * 4;
    float* nxyz = (float*)(ws + off); off += (size_t)B * S * 3 * 4;
    int* gidxp = (int*)(ws + off); off += (size_t)B * S * K * 4;
    unsigned short* WF = (unsigned short*)(ws + off); off += 77824 * 2;
    float* biasv = (float*)(ws + off); off += DIM * 4;

    k_mega<<<8 + NT_BLOCKS + 19 + 1, 256, 0, stream>>>(
        xyz, points, Wc, bc, gamma, beta, mean, var, Wp, bp, Wq, Wk, Wv, Wo,
        ptsT, nxyz, out_xyz, WF, biasv);
    k_ball<<<B * S / 4, 256, 0, stream>>>(xyz, nxyz, gidxp);
    k_group<<<B * S, 256, 0, stream>>>(ptsT, nxyz, gidxp, WF, biasv, out_pts);
}

// Round 8
// 936.719 us; speedup vs baseline: 1.1588x; 1.1588x over previous
//
#include <hip/hip_runtime.h>
#include <math.h>

#define B 8
#define N 4096
#define S 1024
#define K 32
#define CIN 64
#define DIM 128
#define NH 4
#define HD 32
#define PTROW 68   // xyz(3) + points(64) + pad(1)
#define NT_BLOCKS 240

typedef __attribute__((ext_vector_type(8))) short bfrag;
typedef __attribute__((ext_vector_type(4))) float f32x4;

#define MFMA(a, b, c) __builtin_amdgcn_mfma_f32_16x16x32_bf16((a), (b), (c), 0, 0, 0)

__device__ __forceinline__ unsigned short f2bf(float f) {
    union { float f; unsigned u; } v; v.f = f;
    unsigned r = v.u + 0x7FFFu + ((v.u >> 16) & 1u);
    return (unsigned short)(r >> 16);
}

// float max DPP step; invalid lanes keep old -> fmax(v,v)=v safe
#define DPPMAXF(var, CTRL) {                                                              \
    int _o = __builtin_amdgcn_update_dpp(__float_as_int(var), __float_as_int(var),        \
                                         CTRL, 0xf, 0xf, false);                          \
    var = fmaxf(var, __int_as_float(_o));                                                 \
}
#define DPPMINU(var, CTRL) {                                                              \
    unsigned _o = (unsigned)__builtin_amdgcn_update_dpp((int)(var), (int)(var),           \
                                                        CTRL, 0xf, 0xf, false);          \
    var = (_o < (var)) ? _o : (var);                                                      \
}

// ---------------- mega kernel (512 thr): FPS (blk<8) | transpose | weight-swizzle | bias ----------------
__global__ __launch_bounds__(512) void k_mega(
    const float* __restrict__ xyz, const float* __restrict__ points,
    const float* __restrict__ Wc, const float* __restrict__ bc,
    const float* __restrict__ gamma, const float* __restrict__ beta,
    const float* __restrict__ mean, const float* __restrict__ var,
    const float* __restrict__ Wp, const float* __restrict__ bp,
    const float* __restrict__ Wq, const float* __restrict__ Wk,
    const float* __restrict__ Wv, const float* __restrict__ Wo,
    float* __restrict__ ptsT, float* __restrict__ nxyz, float* __restrict__ out_xyz,
    unsigned short* __restrict__ WF, float* __restrict__ biasv) {
    __shared__ __align__(16) float pxyz4[N * 4];  // 64 KB: [n] = {x,y,z,pad}
    __shared__ float cent[S * 3];                 // 12 KB
    __shared__ __align__(16) unsigned long long wbuf[2][8];
    const int tid = threadIdx.x;
    int blk = blockIdx.x;

    if (blk < 8) {
        // ================= FPS: 8 waves (2/SIMD fills issue cadence), 8 pts/thread in regs =================
        const int b = blk;
        const float* X = xyz + (size_t)b * 3 * N;
        float px[8], py[8], pz[8], pd[8];
#pragma unroll
        for (int i = 0; i < 8; i++) {
            int n = tid + i * 512;
            px[i] = X[n]; py[i] = X[N + n]; pz[i] = X[2 * N + n];
            pxyz4[n * 4 + 0] = px[i];
            pxyz4[n * 4 + 1] = py[i];
            pxyz4[n * 4 + 2] = pz[i];
            pd[i] = 1e10f;
        }
        __syncthreads();
        float cx = pxyz4[0], cy = pxyz4[1], cz = pxyz4[2];

        for (int t = 0; t < S; t++) {
            if (tid == 0) { cent[t * 3] = cx; cent[t * 3 + 1] = cy; cent[t * 3 + 2] = cz; }
            if (t == S - 1) break;

            float bv = -1.0f; int slot = 0;
#pragma unroll
            for (int i = 0; i < 8; i++) {
                float dx = px[i] - cx, dy = py[i] - cy, dz = pz[i] - cz;
                // match XLA/np: (dx*dx + dy*dy) + dz*dz, no FMA contraction
                float d = __fadd_rn(__fadd_rn(__fmul_rn(dx, dx), __fmul_rn(dy, dy)), __fmul_rn(dz, dz));
                float pn = fminf(pd[i], d);
                pd[i] = pn;
                bool gt = pn > bv;          // strict >: first slot wins within thread
                bv = gt ? pn : bv;
                slot = gt ? i : slot;
            }
            // wave float-max (lane63 gets wave max)
            float m = bv;
            DPPMAXF(m, 0x111)  // row_shr:1
            DPPMAXF(m, 0x112)  // row_shr:2
            DPPMAXF(m, 0x114)  // row_shr:4
            DPPMAXF(m, 0x118)  // row_shr:8
            DPPMAXF(m, 0x142)  // row_bcast:15
            DPPMAXF(m, 0x143)  // row_bcast:31
            float wmax = __int_as_float(__builtin_amdgcn_readlane(__float_as_int(m), 63));
            // min index among tied lanes
            unsigned bi = (unsigned)(tid + (slot << 9));
            unsigned bic = (bv == wmax) ? bi : 0xFFFFFFFFu;
            DPPMINU(bic, 0x111)
            DPPMINU(bic, 0x112)
            DPPMINU(bic, 0x114)
            DPPMINU(bic, 0x118)
            DPPMINU(bic, 0x142)
            DPPMINU(bic, 0x143)
            if ((tid & 63) == 63) {
                unsigned long long key =
                    ((unsigned long long)__float_as_uint(wmax) << 32) | (0xFFFFFFFFu - bic);
                wbuf[t & 1][tid >> 6] = key;
            }
            __syncthreads();
            ulonglong2 p01 = *(const ulonglong2*)&wbuf[t & 1][0];
            ulonglong2 p23 = *(const ulonglong2*)&wbuf[t & 1][2];
            ulonglong2 p45 = *(const ulonglong2*)&wbuf[t & 1][4];
            ulonglong2 p67 = *(const ulonglong2*)&wbuf[t & 1][6];
            unsigned long long m0 = p01.x > p01.y ? p01.x : p01.y;
            unsigned long long m1 = p23.x > p23.y ? p23.x : p23.y;
            unsigned long long m2 = p45.x > p45.y ? p45.x : p45.y;
            unsigned long long m3 = p67.x > p67.y ? p67.x : p67.y;
            unsigned long long mA = m0 > m1 ? m0 : m1;
            unsigned long long mB = m2 > m3 ? m2 : m3;
            unsigned long long km = mA > mB ? mA : mB;
            int best = (int)(0xFFFFFFFFu - (unsigned)km);
            const float4 pc = *(const float4*)&pxyz4[best * 4];
            cx = pc.x; cy = pc.y; cz = pc.z;
        }
        __syncthreads();
        for (int i = tid; i < S; i += 512) {
            float a = cent[i * 3], c1 = cent[i * 3 + 1], c2 = cent[i * 3 + 2];
            nxyz[(b * S + i) * 3 + 0] = a;
            nxyz[(b * S + i) * 3 + 1] = c1;
            nxyz[(b * S + i) * 3 + 2] = c2;
            out_xyz[b * 3 * S + i] = a;
            out_xyz[b * 3 * S + S + i] = c1;
            out_xyz[b * 3 * S + 2 * S + i] = c2;
        }
        return;
    }
    blk -= 8;
    if (blk < NT_BLOCKS) {
        // ================= transpose (round-6 scheme: coalesced writes, L2-absorbed strided reads) =================
        const int total = B * N * PTROW;
        for (int idx = blk * 512 + tid; idx < total; idx += NT_BLOCKS * 512) {
            int c = idx % PTROW;
            int n = (idx / PTROW) % N;
            int b = idx / (PTROW * N);
            float v = 0.0f;
            if (c < 3) v = xyz[(b * 3 + c) * N + n];
            else if (c < 67) v = points[(b * CIN + (c - 3)) * N + n];
            ptsT[idx] = v;
        }
        return;
    }
    blk -= NT_BLOCKS;
    if (blk < 19) {
        // ================= weight swizzle into MFMA B-fragment order (512 thr: one pass) =================
        int mat, kt, base;
        if (blk < 3) { mat = 0; kt = blk; base = 0; }
        else { mat = 1 + (blk - 3) / 4; kt = (blk - 3) % 4; base = 12288 + (mat - 1) * 16384; }
        const float* W = (mat == 1) ? Wq : (mat == 2) ? Wk : (mat == 3) ? Wv : Wo;
        const int lane = tid & 63;
        const int gnt = tid >> 6;
        int n = gnt * 16 + (lane & 15);
        int k0 = kt * 32 + (lane >> 4) * 8;
        unsigned short* dst = WF + base + (size_t)((kt * 8 + gnt) * 64 + lane) * 8;
        float a = (mat == 0) ? (gamma[n] / sqrtf(var[n] + 1e-5f)) : 0.0f;
#pragma unroll
        for (int i = 0; i < 8; i++) {
            int k = k0 + i;
            float v;
            if (mat == 0) v = (k < 67) ? Wc[n * 67 + k] * a : (k < 70) ? Wp[(k - 67) * 128 + n] : 0.0f;
            else v = W[k * 128 + n];
            dst[i] = f2bf(v);
        }
        return;
    }
    // ================= bias =================
    if (tid < DIM) {
        float a = gamma[tid] / sqrtf(var[tid] + 1e-5f);
        biasv[tid] = bc[tid] * a + beta[tid] - mean[tid] * a + bp[tid];
    }
}

// ---------------- ball query ----------------
__global__ void k_ball(const float* __restrict__ xyz, const float* __restrict__ nxyz,
                       int* __restrict__ gidx) {
    const int g = blockIdx.x * 4 + (threadIdx.x >> 6);
    const int lane = threadIdx.x & 63;
    const int b = g >> 10;
    const float* X = xyz + (size_t)b * 3 * N;
    float cx = nxyz[g * 3 + 0], cy = nxyz[g * 3 + 1], cz = nxyz[g * 3 + 2];
    int cnt = 0;
    int first = -1;
    for (int base = 0; base < N && cnt < K; base += 64) {
        int n = base + lane;
        float dx = cx - X[n], dy = cy - X[N + n], dz = cz - X[2 * N + n];
        float d = __fadd_rn(__fadd_rn(__fmul_rn(dx, dx), __fmul_rn(dy, dy)), __fmul_rn(dz, dz));
        bool in = (d <= 0.04f);
        unsigned long long m = __ballot(in);
        int pre = __popcll(m & ((1ull << lane) - 1ull));
        if (in && cnt + pre < K) gidx[g * K + cnt + pre] = n;
        if (first < 0 && m) first = base + (int)__ffsll((unsigned long long)m) - 1;
        cnt += __popcll(m);
    }
    if (cnt < K) {
        for (int i = cnt + lane; i < K; i += 64) gidx[g * K + i] = first;
    }
}

// ---------------- fused group kernel, MFMA version ----------------
#define LDS_X   0        // [32][128] bf16 swizzled: x -> P
#define LDS_A   8192     // [32][128] bf16 swizzled: feat -> q -> o
#define LDS_K   16384    // [32][128] bf16 swizzled: k
#define LDS_VT  24576    // v_t [128][56] bf16 (112B rows): v transposed
#define LDS_MISC 38912   // nidx[32] int, ctr[3] float
#define LDS_TOTAL 39056

#define LDSA_READ(off, row, colb) \
    (*(const bfrag*)(smem + (off) + ((row) << 8) + ((colb) ^ (((row) & 7) << 4))))
#define LDS_ST16(off, row, colb, val) \
    (*(unsigned short*)(smem + (off) + ((row) << 8) + ((colb) ^ (((row) & 7) << 4))) = (val))

__global__ __launch_bounds__(256, 4) void k_group(
    const float* __restrict__ ptsT, const float* __restrict__ nxyz,
    const int* __restrict__ gidx, const unsigned short* __restrict__ WF,
    const float* __restrict__ bias, float* __restrict__ outp) {
    __shared__ __align__(16) char smem[LDS_TOTAL];
    const int g = blockIdx.x, b = g >> 10, s = g & 1023;
    const int tid = threadIdx.x;
    const int w = tid >> 6, l = tid & 63;
    const int lane16 = l & 15, lquad = l >> 4;
    const int ncol = w * 32;

    int* nidx = (int*)(smem + LDS_MISC);
    float* ctr = (float*)(smem + LDS_MISC + 128);

    if (tid < K) nidx[tid] = gidx[g * K + tid];
    if (tid >= 64 && tid < 67) ctr[tid - 64] = nxyz[g * 3 + (tid - 64)];
    for (int i = tid; i < 32 * 32; i += 256) {
        int p = i >> 5, c = 64 + (i & 31);
        LDS_ST16(LDS_A, p, c * 2, (unsigned short)0);
    }
    __syncthreads();

    {
        const int p = tid >> 3, j = tid & 7;
        const float* src = ptsT + (size_t)(b * N + nidx[p]) * PTROW;
        float c0 = ctr[0], c1 = ctr[1], c2 = ctr[2];
        for (int c = j; c < 70; c += 8) {
            float v;
            if (c < 3) v = src[c] - (c == 0 ? c0 : c == 1 ? c1 : c2);
            else if (c < 67) v = src[c];
            else v = src[c - 67];
            LDS_ST16(LDS_A, p, c * 2, f2bf(v));
        }
    }
    __syncthreads();

    // ---- GEMM1: x = feat @ Wall + bias ----
    f32x4 accx[2][2];
    {
        float bv0 = bias[ncol + lane16], bv1 = bias[ncol + 16 + lane16];
        accx[0][0] = f32x4{bv0, bv0, bv0, bv0}; accx[1][0] = accx[0][0];
        accx[0][1] = f32x4{bv1, bv1, bv1, bv1}; accx[1][1] = accx[0][1];
        const bfrag* WallF = (const bfrag*)WF;
#pragma unroll
        for (int kt = 0; kt < 3; kt++) {
            bfrag a0 = LDSA_READ(LDS_A, lane16, kt * 64 + lquad * 16);
            bfrag a1 = LDSA_READ(LDS_A, 16 + lane16, kt * 64 + lquad * 16);
            bfrag b0 = WallF[(kt * 8 + w * 2 + 0) * 64 + l];
            bfrag b1 = WallF[(kt * 8 + w * 2 + 1) * 64 + l];
            accx[0][0] = MFMA(a0, b0, accx[0][0]);
            accx[0][1] = MFMA(a0, b1, accx[0][1]);
            accx[1][0] = MFMA(a1, b0, accx[1][0]);
            accx[1][1] = MFMA(a1, b1, accx[1][1]);
        }
#pragma unroll
        for (int mt = 0; mt < 2; mt++)
#pragma unroll
            for (int nt = 0; nt < 2; nt++)
#pragma unroll
                for (int r = 0; r < 4; r++)
                    LDS_ST16(LDS_X, mt * 16 + lquad * 4 + r, (ncol + nt * 16 + lane16) * 2,
                             f2bf(accx[mt][nt][r]));
    }
    __syncthreads();

    // ---- GEMM2-4: q,k,v = x @ {Wq,Wk,Wv} ----
    {
        const bfrag* WQF = (const bfrag*)(WF + 12288);
        const bfrag* WKF = (const bfrag*)(WF + 28672);
        const bfrag* WVF = (const bfrag*)(WF + 45056);
#pragma unroll
        for (int m = 0; m < 3; m++) {
            const bfrag* BW = (m == 0) ? WQF : (m == 1) ? WKF : WVF;
            f32x4 acc[2][2] = {};
#pragma unroll
            for (int kt = 0; kt < 4; kt++) {
                bfrag a0 = LDSA_READ(LDS_X, lane16, kt * 64 + lquad * 16);
                bfrag a1 = LDSA_READ(LDS_X, 16 + lane16, kt * 64 + lquad * 16);
                bfrag b0 = BW[(kt * 8 + w * 2 + 0) * 64 + l];
                bfrag b1 = BW[(kt * 8 + w * 2 + 1) * 64 + l];
                acc[0][0] = MFMA(a0, b0, acc[0][0]);
                acc[0][1] = MFMA(a0, b1, acc[0][1]);
                acc[1][0] = MFMA(a1, b0, acc[1][0]);
                acc[1][1] = MFMA(a1, b1, acc[1][1]);
            }
            if (m < 2) {
                int dst = (m == 0) ? LDS_A : LDS_K;
#pragma unroll
                for (int mt = 0; mt < 2; mt++)
#pragma unroll
                    for (int nt = 0; nt < 2; nt++)
#pragma unroll
                        for (int r = 0; r < 4; r++)
                            LDS_ST16(dst, mt * 16 + lquad * 4 + r, (ncol + nt * 16 + lane16) * 2,
                                     f2bf(acc[mt][nt][r]));
            } else {
#pragma unroll
                for (int mt = 0; mt < 2; mt++)
#pragma unroll
                    for (int nt = 0; nt < 2; nt++)
#pragma unroll
                        for (int r = 0; r < 4; r++) {
                            int d = ncol + nt * 16 + lane16;
                            int j = mt * 16 + lquad * 4 + r;
                            *(unsigned short*)(smem + LDS_VT + d * 112 + j * 2) = f2bf(acc[mt][nt][r]);
                        }
            }
        }
    }
    __syncthreads();

    // ---- scores (head h = w), in-register softmax, P -> LDS_X, PV, o -> LDS_A ----
    {
        const int h = w;
        const int hb = h * 64;
        bfrag aq0 = LDSA_READ(LDS_A, lane16, hb + lquad * 16);
        bfrag aq1 = LDSA_READ(LDS_A, 16 + lane16, hb + lquad * 16);
        bfrag bk0 = LDSA_READ(LDS_K, lane16, hb + lquad * 16);
        bfrag bk1 = LDSA_READ(LDS_K, 16 + lane16, hb + lquad * 16);
        f32x4 sc[2][2] = {};
        sc[0][0] = MFMA(aq0, bk0, sc[0][0]);
        sc[0][1] = MFMA(aq0, bk1, sc[0][1]);
        sc[1][0] = MFMA(aq1, bk0, sc[1][0]);
        sc[1][1] = MFMA(aq1, bk1, sc[1][1]);

        const float scale = 0.17677669529663687f;
        float p_[2][2][4];
        float mx[2][4], sm[2][4];
#pragma unroll
        for (int mt = 0; mt < 2; mt++)
#pragma unroll
            for (int r = 0; r < 4; r++) {
                p_[mt][0][r] = sc[mt][0][r] * scale;
                p_[mt][1][r] = sc[mt][1][r] * scale;
                mx[mt][r] = fmaxf(p_[mt][0][r], p_[mt][1][r]);
            }
#pragma unroll
        for (int d = 1; d < 16; d <<= 1)
#pragma unroll
            for (int mt = 0; mt < 2; mt++)
#pragma unroll
                for (int r = 0; r < 4; r++)
                    mx[mt][r] = fmaxf(mx[mt][r], __shfl_xor(mx[mt][r], d));
#pragma unroll
        for (int mt = 0; mt < 2; mt++)
#pragma unroll
            for (int r = 0; r < 4; r++) {
                float e0 = __expf(p_[mt][0][r] - mx[mt][r]);
                float e1 = __expf(p_[mt][1][r] - mx[mt][r]);
                p_[mt][0][r] = e0; p_[mt][1][r] = e1;
                sm[mt][r] = e0 + e1;
            }
#pragma unroll
        for (int d = 1; d < 16; d <<= 1)
#pragma unroll
            for (int mt = 0; mt < 2; mt++)
#pragma unroll
                for (int r = 0; r < 4; r++)
                    sm[mt][r] += __shfl_xor(sm[mt][r], d);
#pragma unroll
        for (int mt = 0; mt < 2; mt++)
#pragma unroll
            for (int r = 0; r < 4; r++) {
                float inv = 1.0f / sm[mt][r];
                int row = mt * 16 + lquad * 4 + r;
                LDS_ST16(LDS_X, row, (h * 32 + lane16) * 2, f2bf(p_[mt][0][r] * inv));
                LDS_ST16(LDS_X, row, (h * 32 + 16 + lane16) * 2, f2bf(p_[mt][1][r] * inv));
            }

        f32x4 oacc[2][2] = {};
        bfrag ap0 = LDSA_READ(LDS_X, lane16, hb + lquad * 16);
        bfrag ap1 = LDSA_READ(LDS_X, 16 + lane16, hb + lquad * 16);
        bfrag bv0 = *(const bfrag*)(smem + LDS_VT + (h * 32 + lane16) * 112 + lquad * 16);
        bfrag bv1 = *(const bfrag*)(smem + LDS_VT + (h * 32 + 16 + lane16) * 112 + lquad * 16);
        oacc[0][0] = MFMA(ap0, bv0, oacc[0][0]);
        oacc[0][1] = MFMA(ap0, bv1, oacc[0][1]);
        oacc[1][0] = MFMA(ap1, bv0, oacc[1][0]);
        oacc[1][1] = MFMA(ap1, bv1, oacc[1][1]);
#pragma unroll
        for (int mt = 0; mt < 2; mt++)
#pragma unroll
            for (int nt = 0; nt < 2; nt++)
#pragma unroll
                for (int r = 0; r < 4; r++)
                    LDS_ST16(LDS_A, mt * 16 + lquad * 4 + r, (h * 32 + nt * 16 + lane16) * 2,
                             f2bf(oacc[mt][nt][r]));
    }
    __syncthreads();

    // ---- GEMM7: out = x + o @ Wo ; maxpool over 32 points ----
    {
        const bfrag* WOF = (const bfrag*)(WF + 61440);
        f32x4 acc[2][2];
#pragma unroll
        for (int mt = 0; mt < 2; mt++)
#pragma unroll
            for (int nt = 0; nt < 2; nt++) acc[mt][nt] = accx[mt][nt];
#pragma unroll
        for (int kt = 0; kt < 4; kt++) {
            bfrag a0 = LDSA_READ(LDS_A, lane16, kt * 64 + lquad * 16);
            bfrag a1 = LDSA_READ(LDS_A, 16 + lane16, kt * 64 + lquad * 16);
            bfrag b0 = WOF[(kt * 8 + w * 2 + 0) * 64 + l];
            bfrag b1 = WOF[(kt * 8 + w * 2 + 1) * 64 + l];
            acc[0][0] = MFMA(a0, b0, acc[0][0]);
            acc[0][1] = MFMA(a0, b1, acc[0][1]);
            acc[1][0] = MFMA(a1, b0, acc[1][0]);
            acc[1][1] = MFMA(a1, b1, acc[1][1]);
        }
        float mnt[2];
#pragma unroll
        for (int nt = 0; nt < 2; nt++) {
            float m = acc[0][nt][0];
#pragma unroll
            for (int r = 1; r < 4; r++) m = fmaxf(m, acc[0][nt][r]);
#pragma unroll
            for (int r = 0; r < 4; r++) m = fmaxf(m, acc[1][nt][r]);
            m = fmaxf(m, __shfl_xor(m, 16));
            m = fmaxf(m, __shfl_xor(m, 32));
            mnt[nt] = m;
        }
        if (lquad == 0) {
#pragma unroll
            for (int nt = 0; nt < 2; nt++) {
                int d = ncol + nt * 16 + lane16;
                outp[((size_t)b * DIM + d) * S + s] = mnt[nt];
            }
        }
    }
}

extern "C" void kernel_launch(void* const* d_in, const int* in_sizes, int n_in,
                              void* d_out, int out_size, void* d_ws, size_t ws_size,
                              hipStream_t stream) {
    const float* xyz = (const float*)d_in[0];
    const float* points = (const float*)d_in[1];
    const float* Wc = (const float*)d_in[2];
    const float* bc = (const float*)d_in[3];
    const float* gamma = (const float*)d_in[4];
    const float* beta = (const float*)d_in[5];
    const float* mean = (const float*)d_in[6];
    const float* var = (const float*)d_in[7];
    const float* Wq = (const float*)d_in[8];
    const float* Wk = (const float*)d_in[9];
    const float* Wv = (const float*)d_in[10];
    const float* Wo = (const float*)d_in[11];
    const float* Wp = (const float*)d_in[12];
    const float* bp = (const float*)d_in[13];

    float* out_xyz = (float*)d_out;
    float* out_pts = out_xyz + B * 3 * S;

    char* ws = (char*)d_ws;
    float* ptsT = (float*)ws;
    size_t off = (size_t)B * N * PTROW * 4;
    float* nxyz = (float*)(ws + off); off += (size_t)B * S * 3 * 4;
    int* gidxp = (int*)(ws + off); off += (size_t)B * S * K * 4;
    unsigned short* WF = (unsigned short*)(ws + off); off += 77824 * 2;
    float* biasv = (float*)(ws + off); off += DIM * 4;

    k_mega<<<8 + NT_BLOCKS + 19 + 1, 512, 0, stream>>>(
        xyz, points, Wc, bc, gamma, beta, mean, var, Wp, bp, Wq, Wk, Wv, Wo,
        ptsT, nxyz, out_xyz, WF, biasv);
    k_ball<<<B * S / 4, 256, 0, stream>>>(xyz, nxyz, gidxp);
    k_group<<<B * S, 256, 0, stream>>>(ptsT, nxyz, gidxp, WF, biasv, out_pts);
}

// Round 9
// 718.026 us; speedup vs baseline: 1.5117x; 1.3046x over previous
//
#include <hip/hip_runtime.h>
#include <math.h>

#define B 8
#define N 4096
#define S 1024
#define K 32
#define CIN 64
#define DIM 128
#define NH 4
#define HD 32
#define PTROW 68   // xyz(3) + points(64) + pad(1)
#define NT_BLOCKS 240

typedef __attribute__((ext_vector_type(8))) short bfrag;
typedef __attribute__((ext_vector_type(4))) float f32x4;

#define MFMA(a, b, c) __builtin_amdgcn_mfma_f32_16x16x32_bf16((a), (b), (c), 0, 0, 0)

__device__ __forceinline__ unsigned short f2bf(float f) {
    union { float f; unsigned u; } v; v.f = f;
    unsigned r = v.u + 0x7FFFu + ((v.u >> 16) & 1u);
    return (unsigned short)(r >> 16);
}

// u64 max DPP step on (hi,lo) pair; shifted-in lanes keep old value (self-compare = no-op)
#define DPPMAXU64(kh, kl, CTRL) {                                                          \
    unsigned _h2 = (unsigned)__builtin_amdgcn_update_dpp((int)(kh), (int)(kh),             \
                                                         CTRL, 0xf, 0xf, false);          \
    unsigned _l2 = (unsigned)__builtin_amdgcn_update_dpp((int)(kl), (int)(kl),             \
                                                         CTRL, 0xf, 0xf, false);          \
    unsigned long long _a = ((unsigned long long)(kh) << 32) | (kl);                       \
    unsigned long long _o = ((unsigned long long)_h2 << 32) | _l2;                         \
    if (_o > _a) { kh = _h2; kl = _l2; }                                                   \
}

// ---------------- mega kernel (256 thr): FPS (blk<8) | transpose | weight-swizzle | bias ----------------
__global__ __launch_bounds__(256) void k_mega(
    const float* __restrict__ xyz, const float* __restrict__ points,
    const float* __restrict__ Wc, const float* __restrict__ bc,
    const float* __restrict__ gamma, const float* __restrict__ beta,
    const float* __restrict__ mean, const float* __restrict__ var,
    const float* __restrict__ Wp, const float* __restrict__ bp,
    const float* __restrict__ Wq, const float* __restrict__ Wk,
    const float* __restrict__ Wv, const float* __restrict__ Wo,
    float* __restrict__ ptsT, float* __restrict__ nxyz, float* __restrict__ out_xyz,
    unsigned short* __restrict__ WF, float* __restrict__ biasv) {
    __shared__ float xs[N], ys[N], zs[N];         // 48 KB
    __shared__ float cent[S * 3];                 // 12 KB
    __shared__ __align__(16) unsigned long long wbuf[2][4];
    const int tid = threadIdx.x;
    int blk = blockIdx.x;

    if (blk < 8) {
        // ================= FPS: 4 waves, 16 pts/thread in regs, u64-key DPP reduce =================
        const int b = blk;
        const float* X = xyz + (size_t)b * 3 * N;
        float px[16], py[16], pz[16], pd[16];
#pragma unroll
        for (int i = 0; i < 16; i++) {
            int n = tid + i * 256;
            px[i] = X[n]; py[i] = X[N + n]; pz[i] = X[2 * N + n];
            xs[n] = px[i]; ys[n] = py[i]; zs[n] = pz[i];
            pd[i] = 1e10f;
        }
        __syncthreads();
        float cx = xs[0], cy = ys[0], cz = zs[0];

        for (int t = 0; t < S; t++) {
            if (tid == 0) { cent[t * 3] = cx; cent[t * 3 + 1] = cy; cent[t * 3 + 2] = cz; }
            if (t == S - 1) break;

            float bv = -1.0f; int slot = 0;
#pragma unroll
            for (int i = 0; i < 16; i++) {
                float dx = px[i] - cx, dy = py[i] - cy, dz = pz[i] - cz;
                // match XLA/np: (dx*dx + dy*dy) + dz*dz, no FMA contraction
                float d = __fadd_rn(__fadd_rn(__fmul_rn(dx, dx), __fmul_rn(dy, dy)), __fmul_rn(dz, dz));
                float pn = fminf(pd[i], d);
                pd[i] = pn;
                bool gt = pn > bv;          // strict >: first slot wins within thread
                bv = gt ? pn : bv;
                slot = gt ? i : slot;
            }
            // packed key: max dist, then min index on ties (dist >= 0 -> bits order-preserving)
            unsigned kh = __float_as_uint(bv);
            unsigned kl = 0xFFFFFFFFu - (unsigned)(tid + (slot << 8));
            // 6-step DPP cascade; lane 63 holds the wave winner
            DPPMAXU64(kh, kl, 0x111)  // row_shr:1
            DPPMAXU64(kh, kl, 0x112)  // row_shr:2
            DPPMAXU64(kh, kl, 0x114)  // row_shr:4
            DPPMAXU64(kh, kl, 0x118)  // row_shr:8
            DPPMAXU64(kh, kl, 0x142)  // row_bcast:15
            DPPMAXU64(kh, kl, 0x143)  // row_bcast:31
            if ((tid & 63) == 63)
                wbuf[t & 1][tid >> 6] = ((unsigned long long)kh << 32) | kl;
            __syncthreads();
            ulonglong2 ab = *(const ulonglong2*)&wbuf[t & 1][0];
            ulonglong2 cd = *(const ulonglong2*)&wbuf[t & 1][2];
            unsigned long long kA = ab.x > ab.y ? ab.x : ab.y;
            unsigned long long kB = cd.x > cd.y ? cd.x : cd.y;
            unsigned long long km = kA > kB ? kA : kB;
            int best = (int)(0xFFFFFFFFu - (unsigned)km);
            cx = xs[best]; cy = ys[best]; cz = zs[best];
        }
        __syncthreads();
        for (int i = tid; i < S; i += 256) {
            float a = cent[i * 3], c1 = cent[i * 3 + 1], c2 = cent[i * 3 + 2];
            nxyz[(b * S + i) * 3 + 0] = a;
            nxyz[(b * S + i) * 3 + 1] = c1;
            nxyz[(b * S + i) * 3 + 2] = c2;
            out_xyz[b * 3 * S + i] = a;
            out_xyz[b * 3 * S + S + i] = c1;
            out_xyz[b * 3 * S + 2 * S + i] = c2;
        }
        return;
    }
    blk -= 8;
    if (blk < NT_BLOCKS) {
        // ================= transpose (coalesced writes, L2-absorbed strided reads) =================
        const int total = B * N * PTROW;
        for (int idx = blk * 256 + tid; idx < total; idx += NT_BLOCKS * 256) {
            int c = idx % PTROW;
            int n = (idx / PTROW) % N;
            int b = idx / (PTROW * N);
            float v = 0.0f;
            if (c < 3) v = xyz[(b * 3 + c) * N + n];
            else if (c < 67) v = points[(b * CIN + (c - 3)) * N + n];
            ptsT[idx] = v;
        }
        return;
    }
    blk -= NT_BLOCKS;
    if (blk < 19) {
        // ================= weight swizzle into MFMA B-fragment order =================
        int mat, kt, base;
        if (blk < 3) { mat = 0; kt = blk; base = 0; }
        else { mat = 1 + (blk - 3) / 4; kt = (blk - 3) % 4; base = 12288 + (mat - 1) * 16384; }
        const float* W = (mat == 1) ? Wq : (mat == 2) ? Wk : (mat == 3) ? Wv : Wo;
        const int lane = tid & 63;
#pragma unroll
        for (int g2 = 0; g2 < 2; g2++) {
            int gnt = (tid >> 6) * 2 + g2;
            int n = gnt * 16 + (lane & 15);
            int k0 = kt * 32 + (lane >> 4) * 8;
            unsigned short* dst = WF + base + (size_t)((kt * 8 + gnt) * 64 + lane) * 8;
            float a = (mat == 0) ? (gamma[n] / sqrtf(var[n] + 1e-5f)) : 0.0f;
#pragma unroll
            for (int i = 0; i < 8; i++) {
                int k = k0 + i;
                float v;
                if (mat == 0) v = (k < 67) ? Wc[n * 67 + k] * a : (k < 70) ? Wp[(k - 67) * 128 + n] : 0.0f;
                else v = W[k * 128 + n];
                dst[i] = f2bf(v);
            }
        }
        return;
    }
    // ================= bias =================
    if (tid < DIM) {
        float a = gamma[tid] / sqrtf(var[tid] + 1e-5f);
        biasv[tid] = bc[tid] * a + beta[tid] - mean[tid] * a + bp[tid];
    }
}

// ---------------- ball query ----------------
__global__ void k_ball(const float* __restrict__ xyz, const float* __restrict__ nxyz,
                       int* __restrict__ gidx) {
    const int g = blockIdx.x * 4 + (threadIdx.x >> 6);
    const int lane = threadIdx.x & 63;
    const int b = g >> 10;
    const float* X = xyz + (size_t)b * 3 * N;
    float cx = nxyz[g * 3 + 0], cy = nxyz[g * 3 + 1], cz = nxyz[g * 3 + 2];
    int cnt = 0;
    int first = -1;
    for (int base = 0; base < N && cnt < K; base += 64) {
        int n = base + lane;
        float dx = cx - X[n], dy = cy - X[N + n], dz = cz - X[2 * N + n];
        float d = __fadd_rn(__fadd_rn(__fmul_rn(dx, dx), __fmul_rn(dy, dy)), __fmul_rn(dz, dz));
        bool in = (d <= 0.04f);
        unsigned long long m = __ballot(in);
        int pre = __popcll(m & ((1ull << lane) - 1ull));
        if (in && cnt + pre < K) gidx[g * K + cnt + pre] = n;
        if (first < 0 && m) first = base + (int)__ffsll((unsigned long long)m) - 1;
        cnt += __popcll(m);
    }
    if (cnt < K) {
        for (int i = cnt + lane; i < K; i += 64) gidx[g * K + i] = first;
    }
}

// ---------------- fused group kernel, MFMA version ----------------
#define LDS_X   0        // [32][128] bf16 swizzled: x -> P
#define LDS_A   8192     // [32][128] bf16 swizzled: feat -> q -> o
#define LDS_K   16384    // [32][128] bf16 swizzled: k
#define LDS_VT  24576    // v_t [128][56] bf16 (112B rows): v transposed
#define LDS_MISC 38912   // nidx[32] int, ctr[3] float
#define LDS_TOTAL 39056

#define LDSA_READ(off, row, colb) \
    (*(const bfrag*)(smem + (off) + ((row) << 8) + ((colb) ^ (((row) & 7) << 4))))
#define LDS_ST16(off, row, colb, val) \
    (*(unsigned short*)(smem + (off) + ((row) << 8) + ((colb) ^ (((row) & 7) << 4))) = (val))

__global__ __launch_bounds__(256, 4) void k_group(
    const float* __restrict__ ptsT, const float* __restrict__ nxyz,
    const int* __restrict__ gidx, const unsigned short* __restrict__ WF,
    const float* __restrict__ bias, float* __restrict__ outp) {
    __shared__ __align__(16) char smem[LDS_TOTAL];
    const int g = blockIdx.x, b = g >> 10, s = g & 1023;
    const int tid = threadIdx.x;
    const int w = tid >> 6, l = tid & 63;
    const int lane16 = l & 15, lquad = l >> 4;
    const int ncol = w * 32;

    int* nidx = (int*)(smem + LDS_MISC);
    float* ctr = (float*)(smem + LDS_MISC + 128);

    if (tid < K) nidx[tid] = gidx[g * K + tid];
    if (tid >= 64 && tid < 67) ctr[tid - 64] = nxyz[g * 3 + (tid - 64)];
    for (int i = tid; i < 32 * 32; i += 256) {
        int p = i >> 5, c = 64 + (i & 31);
        LDS_ST16(LDS_A, p, c * 2, (unsigned short)0);
    }
    __syncthreads();

    {
        const int p = tid >> 3, j = tid & 7;
        const float* src = ptsT + (size_t)(b * N + nidx[p]) * PTROW;
        float c0 = ctr[0], c1 = ctr[1], c2 = ctr[2];
        for (int c = j; c < 70; c += 8) {
            float v;
            if (c < 3) v = src[c] - (c == 0 ? c0 : c == 1 ? c1 : c2);
            else if (c < 67) v = src[c];
            else v = src[c - 67];
            LDS_ST16(LDS_A, p, c * 2, f2bf(v));
        }
    }
    __syncthreads();

    // ---- GEMM1: x = feat @ Wall + bias ----
    f32x4 accx[2][2];
    {
        float bv0 = bias[ncol + lane16], bv1 = bias[ncol + 16 + lane16];
        accx[0][0] = f32x4{bv0, bv0, bv0, bv0}; accx[1][0] = accx[0][0];
        accx[0][1] = f32x4{bv1, bv1, bv1, bv1}; accx[1][1] = accx[0][1];
        const bfrag* WallF = (const bfrag*)WF;
#pragma unroll
        for (int kt = 0; kt < 3; kt++) {
            bfrag a0 = LDSA_READ(LDS_A, lane16, kt * 64 + lquad * 16);
            bfrag a1 = LDSA_READ(LDS_A, 16 + lane16, kt * 64 + lquad * 16);
            bfrag b0 = WallF[(kt * 8 + w * 2 + 0) * 64 + l];
            bfrag b1 = WallF[(kt * 8 + w * 2 + 1) * 64 + l];
            accx[0][0] = MFMA(a0, b0, accx[0][0]);
            accx[0][1] = MFMA(a0, b1, accx[0][1]);
            accx[1][0] = MFMA(a1, b0, accx[1][0]);
            accx[1][1] = MFMA(a1, b1, accx[1][1]);
        }
#pragma unroll
        for (int mt = 0; mt < 2; mt++)
#pragma unroll
            for (int nt = 0; nt < 2; nt++)
#pragma unroll
                for (int r = 0; r < 4; r++)
                    LDS_ST16(LDS_X, mt * 16 + lquad * 4 + r, (ncol + nt * 16 + lane16) * 2,
                             f2bf(accx[mt][nt][r]));
    }
    __syncthreads();

    // ---- GEMM2-4: q,k,v = x @ {Wq,Wk,Wv} ----
    {
        const bfrag* WQF = (const bfrag*)(WF + 12288);
        const bfrag* WKF = (const bfrag*)(WF + 28672);
        const bfrag* WVF = (const bfrag*)(WF + 45056);
#pragma unroll
        for (int m = 0; m < 3; m++) {
            const bfrag* BW = (m == 0) ? WQF : (m == 1) ? WKF : WVF;
            f32x4 acc[2][2] = {};
#pragma unroll
            for (int kt = 0; kt < 4; kt++) {
                bfrag a0 = LDSA_READ(LDS_X, lane16, kt * 64 + lquad * 16);
                bfrag a1 = LDSA_READ(LDS_X, 16 + lane16, kt * 64 + lquad * 16);
                bfrag b0 = BW[(kt * 8 + w * 2 + 0) * 64 + l];
                bfrag b1 = BW[(kt * 8 + w * 2 + 1) * 64 + l];
                acc[0][0] = MFMA(a0, b0, acc[0][0]);
                acc[0][1] = MFMA(a0, b1, acc[0][1]);
                acc[1][0] = MFMA(a1, b0, acc[1][0]);
                acc[1][1] = MFMA(a1, b1, acc[1][1]);
            }
            if (m < 2) {
                int dst = (m == 0) ? LDS_A : LDS_K;
#pragma unroll
                for (int mt = 0; mt < 2; mt++)
#pragma unroll
                    for (int nt = 0; nt < 2; nt++)
#pragma unroll
                        for (int r = 0; r < 4; r++)
                            LDS_ST16(dst, mt * 16 + lquad * 4 + r, (ncol + nt * 16 + lane16) * 2,
                                     f2bf(acc[mt][nt][r]));
            } else {
#pragma unroll
                for (int mt = 0; mt < 2; mt++)
#pragma unroll
                    for (int nt = 0; nt < 2; nt++)
#pragma unroll
                        for (int r = 0; r < 4; r++) {
                            int d = ncol + nt * 16 + lane16;
                            int j = mt * 16 + lquad * 4 + r;
                            *(unsigned short*)(smem + LDS_VT + d * 112 + j * 2) = f2bf(acc[mt][nt][r]);
                        }
            }
        }
    }
    __syncthreads();

    // ---- scores (head h = w), in-register softmax, P -> LDS_X, PV, o -> LDS_A ----
    {
        const int h = w;
        const int hb = h * 64;
        bfrag aq0 = LDSA_READ(LDS_A, lane16, hb + lquad * 16);
        bfrag aq1 = LDSA_READ(LDS_A, 16 + lane16, hb + lquad * 16);
        bfrag bk0 = LDSA_READ(LDS_K, lane16, hb + lquad * 16);
        bfrag bk1 = LDSA_READ(LDS_K, 16 + lane16, hb + lquad * 16);
        f32x4 sc[2][2] = {};
        sc[0][0] = MFMA(aq0, bk0, sc[0][0]);
        sc[0][1] = MFMA(aq0, bk1, sc[0][1]);
        sc[1][0] = MFMA(aq1, bk0, sc[1][0]);
        sc[1][1] = MFMA(aq1, bk1, sc[1][1]);

        const float scale = 0.17677669529663687f;
        float p_[2][2][4];
        float mx[2][4], sm[2][4];
#pragma unroll
        for (int mt = 0; mt < 2; mt++)
#pragma unroll
            for (int r = 0; r < 4; r++) {
                p_[mt][0][r] = sc[mt][0][r] * scale;
                p_[mt][1][r] = sc[mt][1][r] * scale;
                mx[mt][r] = fmaxf(p_[mt][0][r], p_[mt][1][r]);
            }
#pragma unroll
        for (int d = 1; d < 16; d <<= 1)
#pragma unroll
            for (int mt = 0; mt < 2; mt++)
#pragma unroll
                for (int r = 0; r < 4; r++)
                    mx[mt][r] = fmaxf(mx[mt][r], __shfl_xor(mx[mt][r], d));
#pragma unroll
        for (int mt = 0; mt < 2; mt++)
#pragma unroll
            for (int r = 0; r < 4; r++) {
                float e0 = __expf(p_[mt][0][r] - mx[mt][r]);
                float e1 = __expf(p_[mt][1][r] - mx[mt][r]);
                p_[mt][0][r] = e0; p_[mt][1][r] = e1;
                sm[mt][r] = e0 + e1;
            }
#pragma unroll
        for (int d = 1; d < 16; d <<= 1)
#pragma unroll
            for (int mt = 0; mt < 2; mt++)
#pragma unroll
                for (int r = 0; r < 4; r++)
                    sm[mt][r] += __shfl_xor(sm[mt][r], d);
#pragma unroll
        for (int mt = 0; mt < 2; mt++)
#pragma unroll
            for (int r = 0; r < 4; r++) {
                float inv = 1.0f / sm[mt][r];
                int row = mt * 16 + lquad * 4 + r;
                LDS_ST16(LDS_X, row, (h * 32 + lane16) * 2, f2bf(p_[mt][0][r] * inv));
                LDS_ST16(LDS_X, row, (h * 32 + 16 + lane16) * 2, f2bf(p_[mt][1][r] * inv));
            }

        f32x4 oacc[2][2] = {};
        bfrag ap0 = LDSA_READ(LDS_X, lane16, hb + lquad * 16);
        bfrag ap1 = LDSA_READ(LDS_X, 16 + lane16, hb + lquad * 16);
        bfrag bv0 = *(const bfrag*)(smem + LDS_VT + (h * 32 + lane16) * 112 + lquad * 16);
        bfrag bv1 = *(const bfrag*)(smem + LDS_VT + (h * 32 + 16 + lane16) * 112 + lquad * 16);
        oacc[0][0] = MFMA(ap0, bv0, oacc[0][0]);
        oacc[0][1] = MFMA(ap0, bv1, oacc[0][1]);
        oacc[1][0] = MFMA(ap1, bv0, oacc[1][0]);
        oacc[1][1] = MFMA(ap1, bv1, oacc[1][1]);
#pragma unroll
        for (int mt = 0; mt < 2; mt++)
#pragma unroll
            for (int nt = 0; nt < 2; nt++)
#pragma unroll
                for (int r = 0; r < 4; r++)
                    LDS_ST16(LDS_A, mt * 16 + lquad * 4 + r, (h * 32 + nt * 16 + lane16) * 2,
                             f2bf(oacc[mt][nt][r]));
    }
    __syncthreads();

    // ---- GEMM7: out = x + o @ Wo ; maxpool over 32 points ----
    {
        const bfrag* WOF = (const bfrag*)(WF + 61440);
        f32x4 acc[2][2];
#pragma unroll
        for (int mt = 0; mt < 2; mt++)
#pragma unroll
            for (int nt = 0; nt < 2; nt++) acc[mt][nt] = accx[mt][nt];
#pragma unroll
        for (int kt = 0; kt < 4; kt++) {
            bfrag a0 = LDSA_READ(LDS_A, lane16, kt * 64 + lquad * 16);
            bfrag a1 = LDSA_READ(LDS_A, 16 + lane16, kt * 64 + lquad * 16);
            bfrag b0 = WOF[(kt * 8 + w * 2 + 0) * 64 + l];
            bfrag b1 = WOF[(kt * 8 + w * 2 + 1) * 64 + l];
            acc[0][0] = MFMA(a0, b0, acc[0][0]);
            acc[0][1] = MFMA(a0, b1, acc[0][1]);
            acc[1][0] = MFMA(a1, b0, acc[1][0]);
            acc[1][1] = MFMA(a1, b1, acc[1][1]);
        }
        float mnt[2];
#pragma unroll
        for (int nt = 0; nt < 2; nt++) {
            float m = acc[0][nt][0];
#pragma unroll
            for (int r = 1; r < 4; r++) m = fmaxf(m, acc[0][nt][r]);
#pragma unroll
            for (int r = 0; r < 4; r++) m = fmaxf(m, acc[1][nt][r]);
            m = fmaxf(m, __shfl_xor(m, 16));
            m = fmaxf(m, __shfl_xor(m, 32));
            mnt[nt] = m;
        }
        if (lquad == 0) {
#pragma unroll
            for (int nt = 0; nt < 2; nt++) {
                int d = ncol + nt * 16 + lane16;
                outp[((size_t)b * DIM + d) * S + s] = mnt[nt];
            }
        }
    }
}

extern "C" void kernel_launch(void* const* d_in, const int* in_sizes, int n_in,
                              void* d_out, int out_size, void* d_ws, size_t ws_size,
                              hipStream_t stream) {
    const float* xyz = (const float*)d_in[0];
    const float* points = (const float*)d_in[1];
    const float* Wc = (const float*)d_in[2];
    const float* bc = (const float*)d_in[3];
    const float* gamma = (const float*)d_in[4];
    const float* beta = (const float*)d_in[5];
    const float* mean = (const float*)d_in[6];
    const float* var = (const float*)d_in[7];
    const float* Wq = (const float*)d_in[8];
    const float* Wk = (const float*)d_in[9];
    const float* Wv = (const float*)d_in[10];
    const float* Wo = (const float*)d_in[11];
    const float* Wp = (const float*)d_in[12];
    const float* bp = (const float*)d_in[13];

    float* out_xyz = (float*)d_out;
    float* out_pts = out_xyz + B * 3 * S;

    char* ws = (char*)d_ws;
    float* ptsT = (float*)ws;
    size_t off = (size_t)B * N * PTROW * 4;
    float* nxyz = (float*)(ws + off); off += (size_t)B * S * 3 * 4;
    int* gidxp = (int*)(ws + off); off += (size_t)B * S * K * 4;
    unsigned short* WF = (unsigned short*)(ws + off); off += 77824 * 2;
    float* biasv = (float*)(ws + off); off += DIM * 4;

    k_mega<<<8 + NT_BLOCKS + 19 + 1, 256, 0, stream>>>(
        xyz, points, Wc, bc, gamma, beta, mean, var, Wp, bp, Wq, Wk, Wv, Wo,
        ptsT, nxyz, out_xyz, WF, biasv);
    k_ball<<<B * S / 4, 256, 0, stream>>>(xyz, nxyz, gidxp);
    k_group<<<B * S, 256, 0, stream>>>(ptsT, nxyz, gidxp, WF, biasv, out_pts);
}